// Round 2
// baseline (333.211 us; speedup 1.0000x reference)
//
#include <hip/hip_runtime.h>

typedef __bf16 bf16;
typedef __attribute__((ext_vector_type(4))) float f32x4;
typedef __attribute__((ext_vector_type(8))) bf16 bf16x8;
typedef __attribute__((ext_vector_type(4))) bf16 bf16x4;

constexpr int Bc = 4, Sc = 1024, Dc = 1024, Hc = 16, DKc = 64;

// ---------------- helpers ----------------

// Stage a 64x64 bf16 tile into swizzled LDS from bf16 or fp32 source.
// Swizzle: element = r*64 + (c ^ ((r&7)<<3))
__device__ __forceinline__ void stage64(bf16* s, const void* g, int ld, int f32src) {
  const int t = threadIdx.x;
#pragma unroll
  for (int i = 0; i < 2; ++i) {
    const int G = t + i * 256;            // granule 0..511, 8 bf16 each
    const int r = G >> 3, gr = G & 7;
    bf16x8 o;
    if (f32src) {
      const float* gp = (const float*)g + (long)r * ld + gr * 8;
      const f32x4 a = *(const f32x4*)gp;
      const f32x4 b = *(const f32x4*)(gp + 4);
      o[0]=(bf16)a[0]; o[1]=(bf16)a[1]; o[2]=(bf16)a[2]; o[3]=(bf16)a[3];
      o[4]=(bf16)b[0]; o[5]=(bf16)b[1]; o[6]=(bf16)b[2]; o[7]=(bf16)b[3];
    } else {
      o = *(const bf16x8*)((const bf16*)g + (long)r * ld + gr * 8);
    }
    *(bf16x8*)(s + r * 64 + ((gr * 8) ^ ((r & 7) << 3))) = o;
  }
}

// MFMA operand fragment (16x16x32 bf16) from swizzled 64x64 LDS tile.
// Gather: lane l, elem j -> col = kofs + c0 + {0..3,16..19}, c0=((l>>4)&3)*4.
__device__ __forceinline__ bf16x8 frag_ld(const bf16* s, int row, int kofs) {
  const int lane = threadIdx.x & 63;
  const int c0 = kofs + (((lane >> 4) & 3) << 2);
  const int sw = (row & 7) << 3;
  union { bf16x8 v8; bf16x4 v4[2]; } u;
  u.v4[0] = *(const bf16x4*)(s + row * 64 + (c0 ^ sw));
  u.v4[1] = *(const bf16x4*)(s + row * 64 + ((c0 + 16) ^ sw));
  return u.v8;
}

// ---------------- weight transpose (fp32 -> bf16 T) ----------------

__global__ __launch_bounds__(256) void transpose_weights(
    const float* __restrict__ Wq, const float* __restrict__ Wk,
    const float* __restrict__ Wv, const float* __restrict__ Wc,
    bf16* __restrict__ WqT, bf16* __restrict__ WkT,
    bf16* __restrict__ WvT, bf16* __restrict__ WcT) {
  const int i = blockIdx.x * 256 + threadIdx.x;
  if (i < 1048576) {                       // WqT[h][dk][d] = Wq[h][d][dk]
    const int h = i >> 16, r = i & 65535, dk = r >> 10, d = r & 1023;
    WqT[i] = (bf16)Wq[(h << 16) + d * 64 + dk];
  } else if (i < 1114112) {                // WkT[dk][d]
    const int j = i - 1048576, dk = j >> 10, d = j & 1023;
    WkT[j] = (bf16)Wk[d * 64 + dk];
  } else if (i < 1179648) {                // WvT[dk][d]
    const int j = i - 1114112, dk = j >> 10, d = j & 1023;
    WvT[j] = (bf16)Wv[d * 64 + dk];
  } else if (i < 1245184) {                // WcT[dk][hdk]
    const int j = i - 1179648, dk = j >> 10, c = j & 1023;
    WcT[j] = (bf16)Wc[c * 64 + dk];
  }
}

// ---------------- generic NT GEMM: C[m][n] = A[m][:K] . BT[n][:K] + bias ----
// flags: bit0 fp32 out; bit1 bias-by-m; bit2 A is fp32; bit3 B is fp32.
__global__ __launch_bounds__(256) void gemm_nt(
    const void* __restrict__ Ab, const void* __restrict__ BTb,
    void* __restrict__ Cb, const float* __restrict__ biasb,
    int K, int ldA, int ldBT, int ldC,
    long aZ, int aZdiv, long bZ, int bZmod, long cZ,
    int biasZ, int biasZmod, int flags) {
  const int aF32 = (flags >> 2) & 1, bF32 = (flags >> 3) & 1;
  const int z = blockIdx.z;
  const char* A  = (const char*)Ab  + (long)(z / aZdiv) * aZ * (aF32 ? 4 : 2);
  const char* BT = (const char*)BTb + (long)(z % bZmod) * bZ * (bF32 ? 4 : 2);
  const float* bias = biasb + (long)(z % biasZmod) * biasZ;
  char* C = (char*)Cb + (long)z * cZ * ((flags & 1) ? 4 : 2);
  const int m0 = blockIdx.x * 64, n0 = blockIdx.y * 64;

  __shared__ bf16 sA[4096];
  __shared__ bf16 sB[4096];

  const int lane = threadIdx.x & 63;
  const int w = threadIdx.x >> 6;

  f32x4 acc[4];
#pragma unroll
  for (int nb = 0; nb < 4; ++nb) acc[nb] = (f32x4){0.f, 0.f, 0.f, 0.f};

  for (int kk = 0; kk < K; kk += 64) {
    __syncthreads();
    stage64(sA, aF32 ? (const void*)((const float*)A + (long)m0 * ldA + kk)
                     : (const void*)((const bf16*)A + (long)m0 * ldA + kk), ldA, aF32);
    stage64(sB, bF32 ? (const void*)((const float*)BT + (long)n0 * ldBT + kk)
                     : (const void*)((const bf16*)BT + (long)n0 * ldBT + kk), ldBT, bF32);
    __syncthreads();
#pragma unroll
    for (int ks = 0; ks < 2; ++ks) {
      const bf16x8 af = frag_ld(sA, 16 * w + (lane & 15), ks * 32);
#pragma unroll
      for (int nb = 0; nb < 4; ++nb) {
        const bf16x8 bfr = frag_ld(sB, nb * 16 + (lane & 15), ks * 32);
        acc[nb] = __builtin_amdgcn_mfma_f32_16x16x32_bf16(af, bfr, acc[nb], 0, 0, 0);
      }
    }
  }

  const int rbase = m0 + 16 * w + ((lane >> 4) << 2);
#pragma unroll
  for (int nb = 0; nb < 4; ++nb) {
    const int col = n0 + nb * 16 + (lane & 15);
    const float bn = (flags & 2) ? 0.f : bias[col];
#pragma unroll
    for (int r = 0; r < 4; ++r) {
      const int row = rbase + r;
      const float v = acc[nb][r] + ((flags & 2) ? bias[row] : bn);
      if (flags & 1) ((float*)C)[(long)row * ldC + col] = v;
      else           ((bf16*)C)[(long)row * ldC + col] = (bf16)v;
    }
  }
}

// ---------------- fused attention ----------------
// Swapped-operand QK^T: sc = mfma(K_frag, Q_frag) -> lane l holds
// score[t = nb*16+(l>>4)*4+r][s = w*16+(l&15)]. exp() kept as packed bf16
// P[16][2] in registers (the A-fragment layout PV needs, same gather as V).
// Loop 2: no recompute -- normalize+store attn (f32x4) and PV from registers.
__global__ __launch_bounds__(256, 2) void attn_kernel(
    const bf16* __restrict__ qproj, const bf16* __restrict__ kproj,
    const bf16* __restrict__ vT, float* __restrict__ attn_out,
    bf16* __restrict__ concat) {
  const int s0 = blockIdx.x * 64;
  const int h = blockIdx.y, b = blockIdx.z;
  const int lane = threadIdx.x & 63;
  const int w = threadIdx.x >> 6;
  const float scale = 0.125f;

  __shared__ bf16 sQ[4096];
  __shared__ bf16 sK[4096];
  __shared__ bf16 sV[4096];

  const bf16* qp = qproj + ((long)(b * Hc + h) * Sc + s0) * DKc;
  const bf16* kp = kproj + (long)b * Sc * DKc;
  const bf16* vp = vT + (long)b * DKc * Sc;
  float* ao = attn_out + ((long)(b * Hc + h) * Sc + s0) * Sc;
  bf16* co = concat + (long)(b * Sc + s0) * (Hc * DKc) + h * DKc;

  stage64(sQ, qp, DKc, 0);

  bf16x8 P[16][2];
  float lsum = 0.f;

  // ---- loop 1: QK^T (swapped), exp -> register P, row sums ----
#pragma unroll
  for (int tc = 0; tc < 16; ++tc) {
    __syncthreads();
    stage64(sK, kp + tc * 64 * DKc, DKc, 0);
    __syncthreads();
    f32x4 sc[4];
#pragma unroll
    for (int nb = 0; nb < 4; ++nb) sc[nb] = (f32x4){0.f, 0.f, 0.f, 0.f};
#pragma unroll
    for (int ks = 0; ks < 2; ++ks) {
      const bf16x8 qf = frag_ld(sQ, w * 16 + (lane & 15), ks * 32);
#pragma unroll
      for (int nb = 0; nb < 4; ++nb) {
        const bf16x8 kf = frag_ld(sK, nb * 16 + (lane & 15), ks * 32);
        sc[nb] = __builtin_amdgcn_mfma_f32_16x16x32_bf16(kf, qf, sc[nb], 0, 0, 0);
      }
    }
    float pe[4][4];
#pragma unroll
    for (int nb = 0; nb < 4; ++nb)
#pragma unroll
      for (int r = 0; r < 4; ++r) {
        pe[nb][r] = __expf(sc[nb][r] * scale);
        lsum += pe[nb][r];
      }
#pragma unroll
    for (int hi = 0; hi < 2; ++hi) {
      bf16x8 pk;
#pragma unroll
      for (int j = 0; j < 4; ++j) {
        pk[j]     = (bf16)pe[2 * hi][j];
        pk[4 + j] = (bf16)pe[2 * hi + 1][j];
      }
      P[tc][hi] = pk;
    }
  }

  lsum += __shfl_xor(lsum, 16, 64);
  lsum += __shfl_xor(lsum, 32, 64);
  const float invl = 1.f / lsum;          // valid for s = w*16 + (lane&15)

  f32x4 oacc[4];
#pragma unroll
  for (int nb = 0; nb < 4; ++nb) oacc[nb] = (f32x4){0.f, 0.f, 0.f, 0.f};

  const int rowl = w * 16 + (lane & 15);
  const int c0q = ((lane >> 4) & 3) * 4;

  // ---- loop 2: attn store + PV, all from register P ----
#pragma unroll
  for (int tc = 0; tc < 16; ++tc) {
    __syncthreads();
    stage64(sV, vp + tc * 64, Sc, 0);     // rows = dk, cols = t-chunk
    __syncthreads();
#pragma unroll
    for (int nb = 0; nb < 4; ++nb) {
      f32x4 av;
#pragma unroll
      for (int r = 0; r < 4; ++r)
        av[r] = (float)P[tc][nb >> 1][(nb & 1) * 4 + r] * invl;
      *(f32x4*)(ao + (long)rowl * Sc + tc * 64 + nb * 16 + c0q) = av;
    }
#pragma unroll
    for (int ks = 0; ks < 2; ++ks) {
#pragma unroll
      for (int nb = 0; nb < 4; ++nb) {
        const bf16x8 vf = frag_ld(sV, nb * 16 + (lane & 15), ks * 32);
        oacc[nb] = __builtin_amdgcn_mfma_f32_16x16x32_bf16(P[tc][ks], vf, oacc[nb], 0, 0, 0);
      }
    }
  }

  // epilogue: normalize PV (invl lives at lane s_local; redistribute), store
  float invo[4];
#pragma unroll
  for (int r = 0; r < 4; ++r)
    invo[r] = __shfl(invl, ((lane >> 4) & 3) * 4 + r, 64);
#pragma unroll
  for (int nb = 0; nb < 4; ++nb) {
#pragma unroll
    for (int r = 0; r < 4; ++r) {
      const int row = w * 16 + ((lane >> 4) & 3) * 4 + r;
      const int col = nb * 16 + (lane & 15);
      co[(long)row * (Hc * DKc) + col] = (bf16)(oacc[nb][r] * invo[r]);
    }
  }
}

// ---------------- launcher ----------------

extern "C" void kernel_launch(void* const* d_in, const int* in_sizes, int n_in,
                              void* d_out, int out_size, void* d_ws, size_t ws_size,
                              hipStream_t stream) {
  const float* query = (const float*)d_in[0];
  const float* key   = (const float*)d_in[1];
  const float* value = (const float*)d_in[2];
  const float* Wq = (const float*)d_in[3];
  const float* bq = (const float*)d_in[4];
  const float* Wk = (const float*)d_in[5];
  const float* bk = (const float*)d_in[6];
  const float* Wv = (const float*)d_in[7];
  const float* bv = (const float*)d_in[8];
  const float* Wc = (const float*)d_in[9];
  const float* bc = (const float*)d_in[10];

  bf16* WqT    = (bf16*)d_ws;              // [H][DK][D]     1M
  bf16* WkT    = WqT + 1048576;            // [DK][D]        64K
  bf16* WvT    = WkT + 65536;              // 64K
  bf16* WcT    = WvT + 65536;              // [DK][H*DK]     64K
  bf16* q_proj = WcT + 65536;              // [B][H][S][DK]  4M
  bf16* k_proj = q_proj + 4194304;         // [B][S][DK]     256K
  bf16* vTp    = k_proj + 262144;          // [B][DK][S]     256K
  bf16* concat = vTp + 262144;             // [B][S][H*DK]   4M

  float* out0 = (float*)d_out;                       // [B][S][DK]
  float* attn = out0 + (long)Bc * Sc * DKc;          // [B][H][S][S]

  transpose_weights<<<4864, 256, 0, stream>>>(Wq, Wk, Wv, Wc, WqT, WkT, WvT, WcT);

  // q_proj: per (b,h): query[b] (fp32) @ WqT[h]^T -> [S][DK] bf16
  gemm_nt<<<dim3(16, 1, 64), 256, 0, stream>>>(
      query, WqT, q_proj, bq, 1024, 1024, 1024, 64,
      (long)Sc * Dc, 16, (long)DKc * Dc, 16, (long)Sc * DKc, DKc, 16, 4);
  // k_proj: per b: key[b] (fp32) @ WkT^T -> [S][DK] bf16
  gemm_nt<<<dim3(16, 1, 4), 256, 0, stream>>>(
      key, WkT, k_proj, bk, 1024, 1024, 1024, 64,
      (long)Sc * Dc, 1, 0L, 1, (long)Sc * DKc, 0, 1, 4);
  // vT: per b: WvT @ value[b]^T -> [DK][S] bf16, bias per-m
  gemm_nt<<<dim3(1, 16, 4), 256, 0, stream>>>(
      WvT, value, vTp, bv, 1024, 1024, 1024, 1024,
      0L, 1, (long)Sc * Dc, 4, (long)DKc * Sc, 0, 1, 2 | 8);

  attn_kernel<<<dim3(16, 16, 4), 256, 0, stream>>>(q_proj, k_proj, vTp, attn, concat);

  // combine: per b: concat[b] @ WcT^T + bc -> fp32 out
  gemm_nt<<<dim3(16, 1, 4), 256, 0, stream>>>(
      concat, WcT, out0, bc, 1024, 1024, 1024, 64,
      (long)Sc * Dc, 1, 0L, 1, (long)Sc * DKc, 0, 1, 1);
}

// Round 3
// 191.309 us; speedup vs baseline: 1.7417x; 1.7417x over previous
//
#include <hip/hip_runtime.h>

typedef __bf16 bf16;
typedef __attribute__((ext_vector_type(4))) float f32x4;
typedef __attribute__((ext_vector_type(8))) bf16 bf16x8;
typedef __attribute__((ext_vector_type(4))) bf16 bf16x4;

constexpr int Bc = 4, Sc = 1024, Dc = 1024, Hc = 16, DKc = 64;

// ---------------- helpers ----------------

// Stage a 64x64 bf16 tile into swizzled LDS from bf16 or fp32 source.
// Swizzle: element = r*64 + (c ^ ((r&7)<<3))
__device__ __forceinline__ void stage64(bf16* s, const void* g, int ld, int f32src) {
  const int t = threadIdx.x;
#pragma unroll
  for (int i = 0; i < 2; ++i) {
    const int G = t + i * 256;            // granule 0..511, 8 bf16 each
    const int r = G >> 3, gr = G & 7;
    bf16x8 o;
    if (f32src) {
      const float* gp = (const float*)g + (long)r * ld + gr * 8;
      const f32x4 a = *(const f32x4*)gp;
      const f32x4 b = *(const f32x4*)(gp + 4);
      o[0]=(bf16)a[0]; o[1]=(bf16)a[1]; o[2]=(bf16)a[2]; o[3]=(bf16)a[3];
      o[4]=(bf16)b[0]; o[5]=(bf16)b[1]; o[6]=(bf16)b[2]; o[7]=(bf16)b[3];
    } else {
      o = *(const bf16x8*)((const bf16*)g + (long)r * ld + gr * 8);
    }
    *(bf16x8*)(s + r * 64 + ((gr * 8) ^ ((r & 7) << 3))) = o;
  }
}

// MFMA operand fragment (16x16x32 bf16) from swizzled 64x64 LDS tile.
__device__ __forceinline__ bf16x8 frag_ld(const bf16* s, int row, int kofs) {
  const int lane = threadIdx.x & 63;
  const int c0 = kofs + (((lane >> 4) & 3) << 2);
  const int sw = (row & 7) << 3;
  union { bf16x8 v8; bf16x4 v4[2]; } u;
  u.v4[0] = *(const bf16x4*)(s + row * 64 + (c0 ^ sw));
  u.v4[1] = *(const bf16x4*)(s + row * 64 + ((c0 + 16) ^ sw));
  return u.v8;
}

// ---------------- weight transpose (fp32 -> bf16 T) ----------------

__global__ __launch_bounds__(256) void transpose_weights(
    const float* __restrict__ Wq, const float* __restrict__ Wk,
    const float* __restrict__ Wv, const float* __restrict__ Wc,
    bf16* __restrict__ WqT, bf16* __restrict__ WkT,
    bf16* __restrict__ WvT, bf16* __restrict__ WcT) {
  const int i = blockIdx.x * 256 + threadIdx.x;
  if (i < 1048576) {                       // WqT[h][dk][d] = Wq[h][d][dk]
    const int h = i >> 16, r = i & 65535, dk = r >> 10, d = r & 1023;
    WqT[i] = (bf16)Wq[(h << 16) + d * 64 + dk];
  } else if (i < 1114112) {                // WkT[dk][d]
    const int j = i - 1048576, dk = j >> 10, d = j & 1023;
    WkT[j] = (bf16)Wk[d * 64 + dk];
  } else if (i < 1179648) {                // WvT[dk][d]
    const int j = i - 1114112, dk = j >> 10, d = j & 1023;
    WvT[j] = (bf16)Wv[d * 64 + dk];
  } else if (i < 1245184) {                // WcT[dk][hdk]
    const int j = i - 1179648, dk = j >> 10, c = j & 1023;
    WcT[j] = (bf16)Wc[c * 64 + dk];
  }
}

// ---------------- merged projection GEMM (Q, K, VT in one dispatch) --------
// blocks [0,1024): q_cat[4096][1024] = query @ WqT^T   (bias by col)
// blocks [1024,1088): k_proj[4096][64] = key @ WkT^T   (bias by col)
// blocks [1088,1152): vTp[b][64][1024] = WvT @ value[b]^T (bias by row)
__global__ __launch_bounds__(256) void proj_kernel(
    const float* __restrict__ query, const float* __restrict__ key,
    const float* __restrict__ value, const bf16* __restrict__ WqT,
    const bf16* __restrict__ WkT, const bf16* __restrict__ WvT,
    const float* __restrict__ bq, const float* __restrict__ bk,
    const float* __restrict__ bv, bf16* __restrict__ q_cat,
    bf16* __restrict__ k_proj, bf16* __restrict__ vTp) {
  const int bid = blockIdx.x;
  const void* A; const void* BT; bf16* C; const float* bias;
  int m0, n0, ldA, ldBT, ldC, aF32, bF32, biasM;
  if (bid < 1024) {
    m0 = (bid >> 4) << 6; n0 = (bid & 15) << 6;
    A = query; ldA = 1024; aF32 = 1;
    BT = WqT;  ldBT = 1024; bF32 = 0;
    C = q_cat; ldC = 1024; bias = bq; biasM = 0;
  } else if (bid < 1088) {
    m0 = (bid - 1024) << 6; n0 = 0;
    A = key;    ldA = 1024; aF32 = 1;
    BT = WkT;   ldBT = 1024; bF32 = 0;
    C = k_proj; ldC = 64; bias = bk; biasM = 0;
  } else {
    const int j = bid - 1088;
    m0 = 0; n0 = (j & 15) << 6;
    A = WvT; ldA = 1024; aF32 = 0;
    BT = value + ((long)(j >> 4) << 20); ldBT = 1024; bF32 = 1;
    C = vTp + ((long)(j >> 4) << 16); ldC = 1024; bias = bv; biasM = 1;
  }

  __shared__ bf16 sA[2][4096];
  __shared__ bf16 sB[2][4096];
  const int lane = threadIdx.x & 63;
  const int w = threadIdx.x >> 6;

  f32x4 acc[4];
#pragma unroll
  for (int nb = 0; nb < 4; ++nb) acc[nb] = (f32x4){0.f, 0.f, 0.f, 0.f};

  // prologue stage kk=0
  stage64(sA[0], aF32 ? (const void*)((const float*)A + (long)m0 * ldA)
                      : (const void*)((const bf16*)A + (long)m0 * ldA), ldA, aF32);
  stage64(sB[0], bF32 ? (const void*)((const float*)BT + (long)n0 * ldBT)
                      : (const void*)((const bf16*)BT + (long)n0 * ldBT), ldBT, bF32);
  __syncthreads();

  for (int it = 0; it < 16; ++it) {
    const int p = it & 1;
    if (it < 15) {
      const int kk = (it + 1) * 64;
      stage64(sA[p ^ 1], aF32 ? (const void*)((const float*)A + (long)m0 * ldA + kk)
                              : (const void*)((const bf16*)A + (long)m0 * ldA + kk), ldA, aF32);
      stage64(sB[p ^ 1], bF32 ? (const void*)((const float*)BT + (long)n0 * ldBT + kk)
                              : (const void*)((const bf16*)BT + (long)n0 * ldBT + kk), ldBT, bF32);
    }
#pragma unroll
    for (int ks = 0; ks < 2; ++ks) {
      const bf16x8 af = frag_ld(sA[p], 16 * w + (lane & 15), ks * 32);
#pragma unroll
      for (int nb = 0; nb < 4; ++nb) {
        const bf16x8 bfr = frag_ld(sB[p], nb * 16 + (lane & 15), ks * 32);
        acc[nb] = __builtin_amdgcn_mfma_f32_16x16x32_bf16(af, bfr, acc[nb], 0, 0, 0);
      }
    }
    __syncthreads();
  }

  const int rbase = m0 + 16 * w + ((lane >> 4) << 2);
#pragma unroll
  for (int nb = 0; nb < 4; ++nb) {
    const int col = n0 + nb * 16 + (lane & 15);
    const float bn = biasM ? 0.f : bias[col];
#pragma unroll
    for (int r = 0; r < 4; ++r) {
      const int row = rbase + r;
      C[(long)row * ldC + col] = (bf16)(acc[nb][r] + (biasM ? bias[row] : bn));
    }
  }
}

// ---------------- combine GEMM (bf16 in, fp32 out) ----------------
__global__ __launch_bounds__(256) void combine_kernel(
    const bf16* __restrict__ concat, const bf16* __restrict__ WcT,
    const float* __restrict__ bc, float* __restrict__ out0) {
  const int m0 = blockIdx.x * 64;
  __shared__ bf16 sA[2][4096];
  __shared__ bf16 sB[2][4096];
  const int lane = threadIdx.x & 63;
  const int w = threadIdx.x >> 6;

  f32x4 acc[4];
#pragma unroll
  for (int nb = 0; nb < 4; ++nb) acc[nb] = (f32x4){0.f, 0.f, 0.f, 0.f};

  stage64(sA[0], concat + (long)m0 * 1024, 1024, 0);
  stage64(sB[0], WcT, 1024, 0);
  __syncthreads();
  for (int it = 0; it < 16; ++it) {
    const int p = it & 1;
    if (it < 15) {
      const int kk = (it + 1) * 64;
      stage64(sA[p ^ 1], concat + (long)m0 * 1024 + kk, 1024, 0);
      stage64(sB[p ^ 1], WcT + kk, 1024, 0);
    }
#pragma unroll
    for (int ks = 0; ks < 2; ++ks) {
      const bf16x8 af = frag_ld(sA[p], 16 * w + (lane & 15), ks * 32);
#pragma unroll
      for (int nb = 0; nb < 4; ++nb) {
        const bf16x8 bfr = frag_ld(sB[p], nb * 16 + (lane & 15), ks * 32);
        acc[nb] = __builtin_amdgcn_mfma_f32_16x16x32_bf16(af, bfr, acc[nb], 0, 0, 0);
      }
    }
    __syncthreads();
  }
  const int rbase = m0 + 16 * w + ((lane >> 4) << 2);
#pragma unroll
  for (int nb = 0; nb < 4; ++nb) {
    const int col = nb * 16 + (lane & 15);
    const float bn = bc[col];
#pragma unroll
    for (int r = 0; r < 4; ++r)
      out0[(long)(rbase + r) * 64 + col] = acc[nb][r] + bn;
  }
}

// ---------------- fused attention (recompute, swapped QK^T) ----------------
// Pass A: lsum only. Pass B: recompute scores, exp once (current tc lives in
// 8 regs), vectorized attn store, PV direct from registers. Ping-pong LDS.
__global__ __launch_bounds__(256, 4) void attn_kernel(
    const bf16* __restrict__ q_cat, const bf16* __restrict__ k_proj,
    const bf16* __restrict__ vT, float* __restrict__ attn_out,
    bf16* __restrict__ concat) {
  const int s0 = blockIdx.x * 64;
  const int h = blockIdx.y, b = blockIdx.z;
  const int lane = threadIdx.x & 63;
  const int w = threadIdx.x >> 6;
  const float scale = 0.125f;

  __shared__ bf16 sQ[4096];
  __shared__ bf16 sK[2][4096];
  __shared__ bf16 sV[2][4096];

  const bf16* qp = q_cat + (long)(b * Sc + s0) * 1024 + h * 64;
  const bf16* kp = k_proj + (long)b * Sc * DKc;
  const bf16* vp = vT + (long)b * DKc * Sc;
  float* ao = attn_out + ((long)(b * Hc + h) * Sc + s0) * Sc;
  bf16* co = concat + (long)(b * Sc + s0) * (Hc * DKc) + h * DKc;

  stage64(sQ, qp, 1024, 0);
  stage64(sK[0], kp, DKc, 0);
  __syncthreads();

  const int rowq = w * 16 + (lane & 15);
  bf16x8 qf[2];
  qf[0] = frag_ld(sQ, rowq, 0);
  qf[1] = frag_ld(sQ, rowq, 32);

  float lsum = 0.f;

  // ---- pass A: row sums only ----
  for (int tc = 0; tc < 16; ++tc) {
    const int p = tc & 1;
    if (tc < 15) stage64(sK[p ^ 1], kp + (long)(tc + 1) * 64 * DKc, DKc, 0);
    f32x4 sc[4];
#pragma unroll
    for (int nb = 0; nb < 4; ++nb) sc[nb] = (f32x4){0.f, 0.f, 0.f, 0.f};
#pragma unroll
    for (int ks = 0; ks < 2; ++ks)
#pragma unroll
      for (int nb = 0; nb < 4; ++nb) {
        const bf16x8 kf = frag_ld(sK[p], nb * 16 + (lane & 15), ks * 32);
        sc[nb] = __builtin_amdgcn_mfma_f32_16x16x32_bf16(kf, qf[ks], sc[nb], 0, 0, 0);
      }
#pragma unroll
    for (int nb = 0; nb < 4; ++nb)
#pragma unroll
      for (int r = 0; r < 4; ++r) lsum += __expf(sc[nb][r] * scale);
    __syncthreads();
  }

  lsum += __shfl_xor(lsum, 16, 64);
  lsum += __shfl_xor(lsum, 32, 64);
  const float invl = 1.f / lsum;          // valid for s = rowq

  f32x4 oacc[4];
#pragma unroll
  for (int nb = 0; nb < 4; ++nb) oacc[nb] = (f32x4){0.f, 0.f, 0.f, 0.f};

  // ---- pass B: recompute, store attn, PV ----
  stage64(sK[0], kp, DKc, 0);
  stage64(sV[0], vp, Sc, 0);
  __syncthreads();
  const int c0q = (lane >> 4) << 2;
  for (int tc = 0; tc < 16; ++tc) {
    const int p = tc & 1;
    if (tc < 15) {
      stage64(sK[p ^ 1], kp + (long)(tc + 1) * 64 * DKc, DKc, 0);
      stage64(sV[p ^ 1], vp + (tc + 1) * 64, Sc, 0);
    }
    f32x4 sc[4];
#pragma unroll
    for (int nb = 0; nb < 4; ++nb) sc[nb] = (f32x4){0.f, 0.f, 0.f, 0.f};
#pragma unroll
    for (int ks = 0; ks < 2; ++ks)
#pragma unroll
      for (int nb = 0; nb < 4; ++nb) {
        const bf16x8 kf = frag_ld(sK[p], nb * 16 + (lane & 15), ks * 32);
        sc[nb] = __builtin_amdgcn_mfma_f32_16x16x32_bf16(kf, qf[ks], sc[nb], 0, 0, 0);
      }
    float pe[4][4];
#pragma unroll
    for (int nb = 0; nb < 4; ++nb)
#pragma unroll
      for (int r = 0; r < 4; ++r) pe[nb][r] = __expf(sc[nb][r] * scale);
    // normalized attn store, 16B per lane per nb
#pragma unroll
    for (int nb = 0; nb < 4; ++nb) {
      f32x4 av;
#pragma unroll
      for (int r = 0; r < 4; ++r) av[r] = pe[nb][r] * invl;
      *(f32x4*)(ao + (long)rowq * Sc + tc * 64 + nb * 16 + c0q) = av;
    }
    // pack to PV A-fragments (already the right layout)
    bf16x8 pa[2];
#pragma unroll
    for (int hi = 0; hi < 2; ++hi)
#pragma unroll
      for (int j = 0; j < 4; ++j) {
        pa[hi][j]     = (bf16)pe[2 * hi][j];
        pa[hi][4 + j] = (bf16)pe[2 * hi + 1][j];
      }
#pragma unroll
    for (int ks = 0; ks < 2; ++ks)
#pragma unroll
      for (int nb = 0; nb < 4; ++nb) {
        const bf16x8 vf = frag_ld(sV[p], nb * 16 + (lane & 15), ks * 32);
        oacc[nb] = __builtin_amdgcn_mfma_f32_16x16x32_bf16(pa[ks], vf, oacc[nb], 0, 0, 0);
      }
    __syncthreads();
  }

  // epilogue: normalize PV, store concat slice
  float invo[4];
#pragma unroll
  for (int r = 0; r < 4; ++r)
    invo[r] = __shfl(invl, ((lane >> 4) << 2) + r, 64);
#pragma unroll
  for (int nb = 0; nb < 4; ++nb) {
#pragma unroll
    for (int r = 0; r < 4; ++r) {
      const int row = w * 16 + ((lane >> 4) << 2) + r;
      const int col = nb * 16 + (lane & 15);
      co[(long)row * (Hc * DKc) + col] = (bf16)(oacc[nb][r] * invo[r]);
    }
  }
}

// ---------------- launcher ----------------

extern "C" void kernel_launch(void* const* d_in, const int* in_sizes, int n_in,
                              void* d_out, int out_size, void* d_ws, size_t ws_size,
                              hipStream_t stream) {
  const float* query = (const float*)d_in[0];
  const float* key   = (const float*)d_in[1];
  const float* value = (const float*)d_in[2];
  const float* Wq = (const float*)d_in[3];
  const float* bq = (const float*)d_in[4];
  const float* Wk = (const float*)d_in[5];
  const float* bk = (const float*)d_in[6];
  const float* Wv = (const float*)d_in[7];
  const float* bv = (const float*)d_in[8];
  const float* Wc = (const float*)d_in[9];
  const float* bc = (const float*)d_in[10];

  bf16* WqT    = (bf16*)d_ws;              // [H*DK][D] = [1024][1024]  1M
  bf16* WkT    = WqT + 1048576;            // [64][1024]
  bf16* WvT    = WkT + 65536;
  bf16* WcT    = WvT + 65536;              // [64][1024]
  bf16* q_cat  = WcT + 65536;              // [4096][1024]  (B,S major)
  bf16* k_proj = q_cat + 4194304;          // [4096][64]
  bf16* vTp    = k_proj + 262144;          // [B][64][1024]
  bf16* concat = vTp + 262144;             // [4096][1024]

  float* out0 = (float*)d_out;                       // [B][S][DK]
  float* attn = out0 + (long)Bc * Sc * DKc;          // [B][H][S][S]

  transpose_weights<<<4864, 256, 0, stream>>>(Wq, Wk, Wv, Wc, WqT, WkT, WvT, WcT);

  proj_kernel<<<1152, 256, 0, stream>>>(query, key, value, WqT, WkT, WvT,
                                        bq, bk, bv, q_cat, k_proj, vTp);

  attn_kernel<<<dim3(16, 16, 4), 256, 0, stream>>>(q_cat, k_proj, vTp, attn, concat);

  combine_kernel<<<64, 256, 0, stream>>>(concat, WcT, bc, out0);
}